// Round 9
// baseline (221.475 us; speedup 1.0000x reference)
//
#include <hip/hip_runtime.h>
#include <math.h>

// Problem constants
#define S_LEN 2048
#define DMODEL 1024
#define NHEAD 16
#define HEADD 64
#define BATCH 2
#define MROWS (BATCH * S_LEN)  // 4096

typedef __attribute__((ext_vector_type(8))) short bf16x8;
typedef __attribute__((ext_vector_type(4))) float f32x4;
typedef __attribute__((ext_vector_type(4))) unsigned short u16x4;

#define LOG2E 1.4426950408889634f

// ---------- helpers ----------
__device__ __forceinline__ unsigned short f2bf(float f) {
  unsigned int u = __float_as_uint(f);
  u += 0x7fffu + ((u >> 16) & 1u);  // round-to-nearest-even
  return (unsigned short)(u >> 16);
}

__device__ __forceinline__ unsigned int pk_bf16(float lo, float hi) {
  unsigned int u;
  asm("v_cvt_pk_bf16_f32 %0, %1, %2" : "=v"(u) : "v"(lo), "v"(hi));
  return u;
}

// async global->LDS, 16B per lane. LDS dest must be wave-uniform base
// (HW writes base + lane*16); global source address is per-lane.
__device__ __forceinline__ void gload_lds16(const void* g, void* l) {
  __builtin_amdgcn_global_load_lds(
      (const __attribute__((address_space(1))) unsigned int*)g,
      (__attribute__((address_space(3))) unsigned int*)l, 16, 0, 0);
}

// ---------- fused prep: fp32->bf16 for x + 4 weights, plus bias table ----------
// grid: [0,4096) x | [4096,8192) weights | [8192,8320) bias
// Bias table is pre-scaled by log2(e): attention softmax runs in exp2 domain.
__global__ void prep_kernel(const float* __restrict__ x,
                            const float* __restrict__ Wq,
                            const float* __restrict__ Wk,
                            const float* __restrict__ Wv,
                            const float* __restrict__ Wo,
                            const float* __restrict__ rel,
                            unsigned short* __restrict__ xb,
                            unsigned short* __restrict__ Wqb,
                            unsigned short* __restrict__ Wkb,
                            unsigned short* __restrict__ Wvb,
                            unsigned short* __restrict__ Wob,
                            unsigned short* __restrict__ bias) {
  int blk = blockIdx.x;
  if (blk < 8192) {
    const float* src;
    unsigned short* dst;
    int i;
    if (blk < 4096) {
      src = x; dst = xb; i = blk * 256 + threadIdx.x;
    } else {
      int wsel = (blk - 4096) >> 10;
      src = (wsel == 0) ? Wq : (wsel == 1) ? Wk : (wsel == 2) ? Wv : Wo;
      dst = (wsel == 0) ? Wqb : (wsel == 1) ? Wkb : (wsel == 2) ? Wvb : Wob;
      i = ((blk - 4096) & 1023) * 256 + threadIdx.x;
    }
    float4 v = ((const float4*)src)[i];
    u16x4 o;
    o.x = f2bf(v.x); o.y = f2bf(v.y); o.z = f2bf(v.z); o.w = f2bf(v.w);
    ((u16x4*)dst)[i] = o;
  } else {
    int i = (blk - 8192) * 256 + threadIdx.x;  // 0..32767
    if (i >= NHEAD * S_LEN) return;
    int d = i & (S_LEN - 1);
    int h = i >> 11;
    int bucket;
    if (d < 16) {
      bucket = d;
    } else {
      float t = logf((float)d * 0.0625f) / 2.0794415416798357f * 16.0f;
      bucket = 16 + (int)t;
      if (bucket > 31) bucket = 31;
    }
    bias[h * S_LEN + d] = f2bf(rel[bucket * NHEAD + h] * LOG2E);
  }
}

// ---------- bf16 GEMM: C[M,N] = A[M,K] * Bt[N,K]^T  (both K-contiguous) ----------
// BM x 128 tile (BM = MREP*32), BK=32, 4 waves (2x2). Double-buffered LDS with
// raw s_barrier (one barrier per K-step); next K-step's global_load_lds flies
// under current compute.
template <typename OT, int MREP>
__global__ __launch_bounds__(256, 3)
void gemm_bt(const unsigned short* __restrict__ A,
             const unsigned short* __restrict__ B0,
             const unsigned short* __restrict__ B1,
             const unsigned short* __restrict__ B2,
             OT* __restrict__ C0, OT* __restrict__ C1, OT* __restrict__ C2,
             int M, int N, int K) {
  constexpr int BM = MREP * 32;
  __shared__ unsigned short As[2][BM * 32];
  __shared__ unsigned short Bs[2][128 * 32];
  const unsigned short* Bt = (blockIdx.z == 0) ? B0 : (blockIdx.z == 1 ? B1 : B2);
  OT* C = (blockIdx.z == 0) ? C0 : (blockIdx.z == 1 ? C1 : C2);
  const int tid = threadIdx.x;
  const int w = tid >> 6, l = tid & 63;
  const int g = l >> 4, c = l & 15;
  const int m0 = blockIdx.y * BM, n0 = blockIdx.x * 128;
  const int wr = (w >> 1) * (BM / 2), wc = (w & 1) * 64;

  f32x4 acc[MREP][4] = {};

  auto stage = [&](int k0, int bu) {
#pragma unroll
    for (int it = 0; it < MREP / 2; ++it) {  // A: BM*4 16B chunks
      int ti = it * 256 + tid;
      int row = ti >> 2, ch = ti & 3;
      gload_lds16(A + (size_t)(m0 + row) * K + k0 + ch * 8,
                  (char*)As[bu] + (it * 256 + w * 64) * 16);
    }
#pragma unroll
    for (int it = 0; it < 2; ++it) {  // B: 512 16B chunks
      int ti = it * 256 + tid;
      int row = ti >> 2, ch = ti & 3;
      gload_lds16(Bt + (size_t)(n0 + row) * K + k0 + ch * 8,
                  (char*)Bs[bu] + (it * 256 + w * 64) * 16);
    }
  };

  stage(0, 0);
  for (int k0 = 0; k0 < K; k0 += 32) {
    const int bu = (k0 >> 5) & 1;
    asm volatile("s_waitcnt vmcnt(0)" ::: "memory");
    __builtin_amdgcn_sched_barrier(0);
    __builtin_amdgcn_s_barrier();
    if (k0 + 32 < K) stage(k0 + 32, bu ^ 1);

    bf16x8 af[MREP], bfr[4];
#pragma unroll
    for (int mf = 0; mf < MREP; ++mf)
      af[mf] = *(const bf16x8*)((const char*)As[bu] + (wr + mf * 16 + c) * 64 + g * 16);
#pragma unroll
    for (int nf = 0; nf < 4; ++nf)
      bfr[nf] = *(const bf16x8*)((const char*)Bs[bu] + (wc + nf * 16 + c) * 64 + g * 16);
#pragma unroll
    for (int mf = 0; mf < MREP; ++mf)
#pragma unroll
      for (int nf = 0; nf < 4; ++nf)
        acc[mf][nf] = __builtin_amdgcn_mfma_f32_16x16x32_bf16(
            af[mf], bfr[nf], acc[mf][nf], 0, 0, 0);
  }

#pragma unroll
  for (int mf = 0; mf < MREP; ++mf)
#pragma unroll
    for (int nf = 0; nf < 4; ++nf)
#pragma unroll
      for (int r = 0; r < 4; ++r) {
        int row = m0 + wr + mf * 16 + g * 4 + r;
        int col = n0 + wc + nf * 16 + c;
        float v = acc[mf][nf][r];
        if constexpr (sizeof(OT) == 2)
          C[(size_t)row * N + col] = (OT)f2bf(v);
        else
          C[(size_t)row * N + col] = v;
      }
}

// ---------- V transpose: V (B*S, D) -> Vt (B,H,HD,S), 64x64 LDS tiles ----------
__global__ void vtrans_kernel(const unsigned short* __restrict__ V,
                              unsigned short* __restrict__ Vt) {
  __shared__ unsigned short tl[64][72];  // 72*2=144B row stride (16B aligned)
  const int tid = threadIdx.x;
  const int bh = blockIdx.y, b = bh >> 4, h = bh & 15;
  const int s0 = blockIdx.x * 64;
  {
    int r = tid >> 2, cq = (tid & 3) * 16;
    const unsigned short* src =
        V + (size_t)(b * S_LEN + s0 + r) * DMODEL + h * HEADD + cq;
    *(bf16x8*)&tl[r][cq] = *(const bf16x8*)src;
    *(bf16x8*)&tl[r][cq + 8] = *(const bf16x8*)(src + 8);
  }
  __syncthreads();
  {
    int hd = tid >> 2, sq = (tid & 3) * 16;
    unsigned short tmp[16];
#pragma unroll
    for (int j = 0; j < 16; ++j) tmp[j] = tl[sq + j][hd];
    unsigned short* dst = Vt + (size_t)(bh * 64 + hd) * S_LEN + s0 + sq;
    *(bf16x8*)dst = *(const bf16x8*)tmp;
    *(bf16x8*)(dst + 8) = *(const bf16x8*)(tmp + 8);
  }
}

// ---------- flash attention, swapped-QK^T in-register softmax ----------
// 1D grid of 1024 blocks (one 64-row q-tile each), XCD-aware decode: L%8
// selects the XCD (measured round-robin), so each XCD owns 4 heads' K/V
// (2 MB, L2-resident). Within an XCD, qt is issued longest-first (LPT) so
// backfill balances the causal triangle. 44 KB LDS -> 3 blocks/CU (12
// resident waves, was 8). Softmax runs in exp2 domain (bias pre-scaled by
// log2e, exp2f instead of __expf). s_setprio(1) wraps the MFMA clusters.
// S^T = mfma(K-rows, Q-rows) -> in-register softmax (15 in-lane ops + 2
// shuffles). Interior tiles (dist >= 113) use saturated-bucket constant
// bias, no mask. P^T via cvt_pk -> ds_write_b64; PV = mfma(Vt-rows,
// P-rows) -> O^T; epilogue transposes via per-wave LDS. KV tile = 64,
// double-buffered, 1 raw barrier per tile; K/V LDS rows XOR-swizzled via
// pre-swizzled global source.
__global__ __launch_bounds__(256, 3)
void attn_kernel(const unsigned short* __restrict__ Q,
                 const unsigned short* __restrict__ K,
                 const unsigned short* __restrict__ Vt,
                 const unsigned short* __restrict__ bias,
                 unsigned short* __restrict__ O) {
  __shared__ unsigned short Ks[2][64 * 64];   // 16 KB
  __shared__ unsigned short Vs[2][64 * 64];   // 16 KB
  __shared__ unsigned short Ps[4][16 * 64];   // 8 KB (P^T staging + O epilogue)
  __shared__ unsigned short bls[S_LEN];       // 4 KB (bf16 bias row, log2e-scaled)
  const int tid = threadIdx.x;
  const int w = tid >> 6, l = tid & 63;
  const int g = l >> 4, c = l & 15;
  // XCD-aware decode: 1024 blocks = 8 XCDs x 128 slots; 4 heads per XCD;
  // qt longest-first within each head.
  const int L = blockIdx.x;
  const int xcd = L & 7, slot = L >> 3;
  const int bh = xcd * 4 + (slot >> 5);
  const int qt = 31 - (slot & 31);
  const int b = bh >> 4, h = bh & 15;
  const unsigned short* Qb = Q + (size_t)b * S_LEN * DMODEL + h * HEADD;
  const unsigned short* Kb = K + (size_t)b * S_LEN * DMODEL + h * HEADD;
  const unsigned short* Vtb = Vt + (size_t)bh * HEADD * S_LEN;

  // stage this head's bias row (4 KB bf16) into LDS; saturated-bucket const
  const float bconst =
      __uint_as_float((unsigned int)bias[h * S_LEN + 1024] << 16);
  {
    const bf16x8* src = (const bf16x8*)(bias + h * S_LEN);
    ((bf16x8*)bls)[tid] = src[tid];
  }

  auto stage = [&](int kv0, int bu) {
#pragma unroll
    for (int it = 0; it < 2; ++it) {
      int ti = it * 256 + tid;
      int row = ti >> 3, ch = ti & 7;
      int sch = ch ^ (row & 7);  // pre-swizzled source chunk
      gload_lds16(Kb + (size_t)(kv0 + row) * DMODEL + sch * 8,
                  (char*)Ks[bu] + (it * 256 + w * 64) * 16);
      gload_lds16(Vtb + (size_t)row * S_LEN + kv0 + sch * 8,
                  (char*)Vs[bu] + (it * 256 + w * 64) * 16);
    }
  };

  const int q0 = qt * 64;
  const int nt = qt + 1;
  const int wrow0 = q0 + w * 16;
  const int qglob = wrow0 + c;  // this lane's q row

  // Q fragments (B-operand rows) in registers
  bf16x8 aq[2];
#pragma unroll
  for (int kh = 0; kh < 2; ++kh)
    aq[kh] = *(const bf16x8*)(Qb + (size_t)qglob * DMODEL + kh * 32 + g * 8);

  f32x4 oacc[4] = {};
  float mreg = -1e30f, lreg = 0.f;

  __syncthreads();  // bls ready
  stage(0, 0);

#pragma unroll 1
  for (int t = 0; t < nt; ++t) {
    const int kv0 = t * 64;
    const int bu = t & 1;
    asm volatile("s_waitcnt vmcnt(0)" ::: "memory");
    __builtin_amdgcn_sched_barrier(0);
    __builtin_amdgcn_s_barrier();
    if (t + 1 < nt) stage((t + 1) * 64, bu ^ 1);

    // ---- S^T = K Q^T : D[row=k_local][col=q] ----
    f32x4 sac[4] = {};
    __builtin_amdgcn_s_setprio(1);
#pragma unroll
    for (int kh = 0; kh < 2; ++kh) {
      bf16x8 bk[4];
#pragma unroll
      for (int nf = 0; nf < 4; ++nf) {
        int row = nf * 16 + c;
        int off = (row * 128 + (kh * 4 + g) * 16) ^ ((row & 7) << 4);
        bk[nf] = *(const bf16x8*)((const char*)Ks[bu] + off);
      }
#pragma unroll
      for (int nf = 0; nf < 4; ++nf)
        sac[nf] = __builtin_amdgcn_mfma_f32_16x16x32_bf16(
            bk[nf], aq[kh], sac[nf], 0, 0, 0);
    }
    __builtin_amdgcn_s_setprio(0);

    // ---- bias + causal mask, exp2 domain (interior: const bias, no mask) ----
    float p[4][4];
    float pmax = -1e30f;
    const float qscale = 0.125f * LOG2E;
    if (kv0 + 176 <= wrow0) {  // wave-uniform: all dists >= 113 -> bucket 31
#pragma unroll
      for (int nf = 0; nf < 4; ++nf)
#pragma unroll
        for (int r = 0; r < 4; ++r) {
          float sv = sac[nf][r] * qscale + bconst;
          p[nf][r] = sv;
          pmax = fmaxf(pmax, sv);
        }
    } else {
#pragma unroll
      for (int nf = 0; nf < 4; ++nf)
#pragma unroll
        for (int r = 0; r < 4; ++r) {
          int kg = kv0 + nf * 16 + g * 4 + r;
          int d = qglob - kg;
          float bv = __uint_as_float((unsigned int)bls[d < 0 ? 0 : d] << 16);
          float sv = (d >= 0) ? sac[nf][r] * qscale + bv : -1e30f;
          p[nf][r] = sv;
          pmax = fmaxf(pmax, sv);
        }
    }
    pmax = fmaxf(pmax, __shfl_xor(pmax, 16));
    pmax = fmaxf(pmax, __shfl_xor(pmax, 32));

    // ---- online softmax, defer-max (skip rescale when growth <= 8/ln2) ----
    if (!__all(pmax - mreg <= 11.5f)) {
      float mnew = fmaxf(mreg, pmax);
      float scl = exp2f(mreg - mnew);
      lreg *= scl;
#pragma unroll
      for (int nh = 0; nh < 4; ++nh)
#pragma unroll
        for (int r = 0; r < 4; ++r) oacc[nh][r] *= scl;
      mreg = mnew;
    }
    float lsum = 0.f;
#pragma unroll
    for (int nf = 0; nf < 4; ++nf)
#pragma unroll
      for (int r = 0; r < 4; ++r) {
        float pv = exp2f(p[nf][r] - mreg);
        p[nf][r] = pv;
        lsum += pv;
      }
    lsum += __shfl_xor(lsum, 16);
    lsum += __shfl_xor(lsum, 32);
    lreg += lsum;

    // ---- P^T -> Ps[w] rows q (bf16, packed pairs, swizzled) ----
#pragma unroll
    for (int nf = 0; nf < 4; ++nf) {
      unsigned int u0 = pk_bf16(p[nf][0], p[nf][1]);
      unsigned int u1 = pk_bf16(p[nf][2], p[nf][3]);
      int off = (c * 128 + nf * 32 + g * 8) ^ ((c & 7) << 4);
      *(uint2*)((char*)Ps[w] + off) = make_uint2(u0, u1);
    }

    // ---- O^T += V^T P^T : mfma(A=Vt rows(hd), B=P rows(q)) ----
    __builtin_amdgcn_s_setprio(1);
#pragma unroll
    for (int kh = 0; kh < 2; ++kh) {
      bf16x8 pa, va[4];
      {
        int off = (c * 128 + kh * 64 + g * 16) ^ ((c & 7) << 4);
        pa = *(const bf16x8*)((const char*)Ps[w] + off);
      }
#pragma unroll
      for (int nh = 0; nh < 4; ++nh) {
        int row = nh * 16 + c;
        int off = (row * 128 + (kh * 4 + g) * 16) ^ ((row & 7) << 4);
        va[nh] = *(const bf16x8*)((const char*)Vs[bu] + off);
      }
#pragma unroll
      for (int nh = 0; nh < 4; ++nh)
        oacc[nh] = __builtin_amdgcn_mfma_f32_16x16x32_bf16(
            va[nh], pa, oacc[nh], 0, 0, 0);
    }
    __builtin_amdgcn_s_setprio(0);
  }

  // ---- epilogue: O^T -> Ps[w] (rows q, cols hd) -> coalesced global ----
  {
    float inv = 1.f / lreg;
#pragma unroll
    for (int nh = 0; nh < 4; ++nh) {
      unsigned int u0 = pk_bf16(oacc[nh][0] * inv, oacc[nh][1] * inv);
      unsigned int u1 = pk_bf16(oacc[nh][2] * inv, oacc[nh][3] * inv);
      int off = (c * 128 + nh * 32 + g * 8) ^ ((c & 7) << 4);
      *(uint2*)((char*)Ps[w] + off) = make_uint2(u0, u1);
    }
    int rowq = l >> 2, ch2 = l & 3;
    int off1 = (rowq * 128 + ch2 * 16) ^ ((rowq & 7) << 4);
    int off2 = (rowq * 128 + (ch2 + 4) * 16) ^ ((rowq & 7) << 4);
    bf16x8 o1 = *(const bf16x8*)((const char*)Ps[w] + off1);
    bf16x8 o2 = *(const bf16x8*)((const char*)Ps[w] + off2);
    unsigned short* orow =
        O + (size_t)(b * S_LEN + wrow0 + rowq) * DMODEL + h * HEADD;
    *(bf16x8*)(orow + ch2 * 8) = o1;
    *(bf16x8*)(orow + (ch2 + 4) * 8) = o2;
  }
}

// ---------- host launcher ----------
extern "C" void kernel_launch(void* const* d_in, const int* in_sizes, int n_in,
                              void* d_out, int out_size, void* d_ws, size_t ws_size,
                              hipStream_t stream) {
  const float* x   = (const float*)d_in[0];
  // d_in[1] causal_mask, d_in[2] padding_mask: causality implemented directly;
  // padding_mask is all-false in this problem.
  const float* Wq  = (const float*)d_in[3];
  const float* Wk  = (const float*)d_in[4];
  const float* Wv  = (const float*)d_in[5];
  const float* Wo  = (const float*)d_in[6];
  const float* rel = (const float*)d_in[7];
  float* out = (float*)d_out;

  char* ws = (char*)d_ws;
  const size_t MB = 1u << 20;
  unsigned short* xb  = (unsigned short*)(ws);            // 8 MB (x bf16)
  unsigned short* Oa  = xb;                               // alias: reused after QKV
  unsigned short* Qb  = (unsigned short*)(ws + 8 * MB);   // 8 MB
  unsigned short* Kb  = (unsigned short*)(ws + 16 * MB);  // 8 MB
  unsigned short* Vb  = (unsigned short*)(ws + 24 * MB);  // 8 MB
  unsigned short* Vtb = (unsigned short*)(ws + 32 * MB);  // 8 MB
  unsigned short* Wqb = (unsigned short*)(ws + 40 * MB);  // 2 MB
  unsigned short* Wkb = (unsigned short*)(ws + 42 * MB);  // 2 MB
  unsigned short* Wvb = (unsigned short*)(ws + 44 * MB);  // 2 MB
  unsigned short* Wob = (unsigned short*)(ws + 46 * MB);  // 2 MB
  unsigned short* bias = (unsigned short*)(ws + 48 * MB); // 64 KB (bf16)

  // fused prep: all fp32->bf16 conversions + bias table (1 launch)
  prep_kernel<<<8320, 256, 0, stream>>>(x, Wq, Wk, Wv, Wo, rel,
                                        xb, Wqb, Wkb, Wvb, Wob, bias);

  // Q, K, V projections (fused: grid.z selects weight/output)
  gemm_bt<unsigned short, 4><<<dim3(8, 32, 3), 256, 0, stream>>>(
      xb, Wqb, Wkb, Wvb, Qb, Kb, Vb, MROWS, DMODEL, DMODEL);

  // V -> Vt (B,H,HD,S) via LDS tiles
  vtrans_kernel<<<dim3(32, 32), 256, 0, stream>>>(Vb, Vtb);

  // attention (XCD-aware 1D grid, LPT triangle, 3 blocks/CU)
  attn_kernel<<<1024, 256, 0, stream>>>(Qb, Kb, Vtb, bias, Oa);

  // output projection (fp32 out), BM=64 -> 512 blocks
  gemm_bt<float, 2><<<dim3(8, 64, 1), 256, 0, stream>>>(
      Oa, Wob, Wob, Wob, out, out, out, MROWS, DMODEL, DMODEL);
}

// Round 11
// 204.042 us; speedup vs baseline: 1.0854x; 1.0854x over previous
//
#include <hip/hip_runtime.h>
#include <math.h>

// Problem constants
#define S_LEN 2048
#define DMODEL 1024
#define NHEAD 16
#define HEADD 64
#define BATCH 2
#define MROWS (BATCH * S_LEN)  // 4096

typedef __attribute__((ext_vector_type(8))) short bf16x8;
typedef __attribute__((ext_vector_type(4))) float f32x4;
typedef __attribute__((ext_vector_type(4))) unsigned short u16x4;

#define LOG2E 1.4426950408889634f

// ---------- helpers ----------
__device__ __forceinline__ unsigned short f2bf(float f) {
  unsigned int u = __float_as_uint(f);
  u += 0x7fffu + ((u >> 16) & 1u);  // round-to-nearest-even
  return (unsigned short)(u >> 16);
}

__device__ __forceinline__ unsigned int pk_bf16(float lo, float hi) {
  unsigned int u;
  asm("v_cvt_pk_bf16_f32 %0, %1, %2" : "=v"(u) : "v"(lo), "v"(hi));
  return u;
}

// async global->LDS, 16B per lane. LDS dest must be wave-uniform base
// (HW writes base + lane*16); global source address is per-lane.
__device__ __forceinline__ void gload_lds16(const void* g, void* l) {
  __builtin_amdgcn_global_load_lds(
      (const __attribute__((address_space(1))) unsigned int*)g,
      (__attribute__((address_space(3))) unsigned int*)l, 16, 0, 0);
}

// ---------- fused prep: fp32->bf16 for x + 4 weights, plus bias table ----------
// grid: [0,4096) x | [4096,8192) weights | [8192,8320) bias
// Bias table is pre-scaled by log2(e): attention softmax runs in exp2 domain.
__global__ void prep_kernel(const float* __restrict__ x,
                            const float* __restrict__ Wq,
                            const float* __restrict__ Wk,
                            const float* __restrict__ Wv,
                            const float* __restrict__ Wo,
                            const float* __restrict__ rel,
                            unsigned short* __restrict__ xb,
                            unsigned short* __restrict__ Wqb,
                            unsigned short* __restrict__ Wkb,
                            unsigned short* __restrict__ Wvb,
                            unsigned short* __restrict__ Wob,
                            unsigned short* __restrict__ bias) {
  int blk = blockIdx.x;
  if (blk < 8192) {
    const float* src;
    unsigned short* dst;
    int i;
    if (blk < 4096) {
      src = x; dst = xb; i = blk * 256 + threadIdx.x;
    } else {
      int wsel = (blk - 4096) >> 10;
      src = (wsel == 0) ? Wq : (wsel == 1) ? Wk : (wsel == 2) ? Wv : Wo;
      dst = (wsel == 0) ? Wqb : (wsel == 1) ? Wkb : (wsel == 2) ? Wvb : Wob;
      i = ((blk - 4096) & 1023) * 256 + threadIdx.x;
    }
    float4 v = ((const float4*)src)[i];
    u16x4 o;
    o.x = f2bf(v.x); o.y = f2bf(v.y); o.z = f2bf(v.z); o.w = f2bf(v.w);
    ((u16x4*)dst)[i] = o;
  } else {
    int i = (blk - 8192) * 256 + threadIdx.x;  // 0..32767
    if (i >= NHEAD * S_LEN) return;
    int d = i & (S_LEN - 1);
    int h = i >> 11;
    int bucket;
    if (d < 16) {
      bucket = d;
    } else {
      float t = logf((float)d * 0.0625f) / 2.0794415416798357f * 16.0f;
      bucket = 16 + (int)t;
      if (bucket > 31) bucket = 31;
    }
    bias[h * S_LEN + d] = f2bf(rel[bucket * NHEAD + h] * LOG2E);
  }
}

// ---------- bf16 GEMM: C[M,N] = A[M,K] * Bt[N,K]^T  (both K-contiguous) ----------
// BM x 128 tile (BM = MREP*32), BK=32, 4 waves (2x2). Double-buffered LDS with
// raw s_barrier (one barrier per K-step); next K-step's global_load_lds flies
// under current compute.
template <typename OT, int MREP>
__global__ __launch_bounds__(256, 3)
void gemm_bt(const unsigned short* __restrict__ A,
             const unsigned short* __restrict__ B0,
             const unsigned short* __restrict__ B1,
             const unsigned short* __restrict__ B2,
             OT* __restrict__ C0, OT* __restrict__ C1, OT* __restrict__ C2,
             int M, int N, int K) {
  constexpr int BM = MREP * 32;
  __shared__ unsigned short As[2][BM * 32];
  __shared__ unsigned short Bs[2][128 * 32];
  const unsigned short* Bt = (blockIdx.z == 0) ? B0 : (blockIdx.z == 1 ? B1 : B2);
  OT* C = (blockIdx.z == 0) ? C0 : (blockIdx.z == 1 ? C1 : C2);
  const int tid = threadIdx.x;
  const int w = tid >> 6, l = tid & 63;
  const int g = l >> 4, c = l & 15;
  const int m0 = blockIdx.y * BM, n0 = blockIdx.x * 128;
  const int wr = (w >> 1) * (BM / 2), wc = (w & 1) * 64;

  f32x4 acc[MREP][4] = {};

  auto stage = [&](int k0, int bu) {
#pragma unroll
    for (int it = 0; it < MREP / 2; ++it) {  // A: BM*4 16B chunks
      int ti = it * 256 + tid;
      int row = ti >> 2, ch = ti & 3;
      gload_lds16(A + (size_t)(m0 + row) * K + k0 + ch * 8,
                  (char*)As[bu] + (it * 256 + w * 64) * 16);
    }
#pragma unroll
    for (int it = 0; it < 2; ++it) {  // B: 512 16B chunks
      int ti = it * 256 + tid;
      int row = ti >> 2, ch = ti & 3;
      gload_lds16(Bt + (size_t)(n0 + row) * K + k0 + ch * 8,
                  (char*)Bs[bu] + (it * 256 + w * 64) * 16);
    }
  };

  stage(0, 0);
  for (int k0 = 0; k0 < K; k0 += 32) {
    const int bu = (k0 >> 5) & 1;
    asm volatile("s_waitcnt vmcnt(0)" ::: "memory");
    __builtin_amdgcn_sched_barrier(0);
    __builtin_amdgcn_s_barrier();
    if (k0 + 32 < K) stage(k0 + 32, bu ^ 1);

    bf16x8 af[MREP], bfr[4];
#pragma unroll
    for (int mf = 0; mf < MREP; ++mf)
      af[mf] = *(const bf16x8*)((const char*)As[bu] + (wr + mf * 16 + c) * 64 + g * 16);
#pragma unroll
    for (int nf = 0; nf < 4; ++nf)
      bfr[nf] = *(const bf16x8*)((const char*)Bs[bu] + (wc + nf * 16 + c) * 64 + g * 16);
#pragma unroll
    for (int mf = 0; mf < MREP; ++mf)
#pragma unroll
      for (int nf = 0; nf < 4; ++nf)
        acc[mf][nf] = __builtin_amdgcn_mfma_f32_16x16x32_bf16(
            af[mf], bfr[nf], acc[mf][nf], 0, 0, 0);
  }

#pragma unroll
  for (int mf = 0; mf < MREP; ++mf)
#pragma unroll
    for (int nf = 0; nf < 4; ++nf)
#pragma unroll
      for (int r = 0; r < 4; ++r) {
        int row = m0 + wr + mf * 16 + g * 4 + r;
        int col = n0 + wc + nf * 16 + c;
        float v = acc[mf][nf][r];
        if constexpr (sizeof(OT) == 2)
          C[(size_t)row * N + col] = (OT)f2bf(v);
        else
          C[(size_t)row * N + col] = v;
      }
}

// ---------- V transpose: V (B*S, D) -> Vt (B,H,HD,S), 64x64 LDS tiles ----------
__global__ void vtrans_kernel(const unsigned short* __restrict__ V,
                              unsigned short* __restrict__ Vt) {
  __shared__ unsigned short tl[64][72];  // 72*2=144B row stride (16B aligned)
  const int tid = threadIdx.x;
  const int bh = blockIdx.y, b = bh >> 4, h = bh & 15;
  const int s0 = blockIdx.x * 64;
  {
    int r = tid >> 2, cq = (tid & 3) * 16;
    const unsigned short* src =
        V + (size_t)(b * S_LEN + s0 + r) * DMODEL + h * HEADD + cq;
    *(bf16x8*)&tl[r][cq] = *(const bf16x8*)src;
    *(bf16x8*)&tl[r][cq + 8] = *(const bf16x8*)(src + 8);
  }
  __syncthreads();
  {
    int hd = tid >> 2, sq = (tid & 3) * 16;
    unsigned short tmp[16];
#pragma unroll
    for (int j = 0; j < 16; ++j) tmp[j] = tl[sq + j][hd];
    unsigned short* dst = Vt + (size_t)(bh * 64 + hd) * S_LEN + s0 + sq;
    *(bf16x8*)dst = *(const bf16x8*)tmp;
    *(bf16x8*)(dst + 8) = *(const bf16x8*)(tmp + 8);
  }
}

// ---------- flash attention, swapped-QK^T in-register softmax ----------
// 1D grid of 1024 blocks (one 64-row q-tile each), XCD-aware decode: L%8
// selects the XCD (measured round-robin), each XCD owns 4 heads' K/V (2 MB,
// L2-resident). GLOBAL LPT within each XCD: slot&3 = head, 31-(slot>>2) =
// qt, so the four longest tiles (32 KV-units) of all four heads launch
// FIRST and backfill blocks are the shortest (round-9 post-mortem: per-head
// LPT left head3's longest block launching last -> 32-unit tail). 44 KB LDS
// -> 3 blocks/CU. exp2-domain softmax; setprio around MFMA clusters.
// S^T = mfma(K-rows, Q-rows) -> in-register softmax. Interior tiles
// (dist >= 113) use saturated-bucket constant bias, no mask. P^T via cvt_pk
// -> ds_write_b64; PV = mfma(Vt-rows, P-rows) -> O^T; epilogue transposes
// via per-wave LDS. KV tile = 64, double-buffered, 1 raw barrier per tile;
// K/V LDS rows XOR-swizzled via pre-swizzled global source.
__global__ __launch_bounds__(256, 3)
void attn_kernel(const unsigned short* __restrict__ Q,
                 const unsigned short* __restrict__ K,
                 const unsigned short* __restrict__ Vt,
                 const unsigned short* __restrict__ bias,
                 unsigned short* __restrict__ O) {
  __shared__ unsigned short Ks[2][64 * 64];   // 16 KB
  __shared__ unsigned short Vs[2][64 * 64];   // 16 KB
  __shared__ unsigned short Ps[4][16 * 64];   // 8 KB (P^T staging + O epilogue)
  __shared__ unsigned short bls[S_LEN];       // 4 KB (bf16 bias row, log2e-scaled)
  const int tid = threadIdx.x;
  const int w = tid >> 6, l = tid & 63;
  const int g = l >> 4, c = l & 15;
  // XCD-aware decode with GLOBAL LPT: 1024 blocks = 8 XCDs x 128 slots;
  // slot&3 = head (4 per XCD), 31-(slot>>2) = qt (longest first).
  const int L = blockIdx.x;
  const int xcd = L & 7, slot = L >> 3;
  const int bh = xcd * 4 + (slot & 3);
  const int qt = 31 - (slot >> 2);
  const int b = bh >> 4, h = bh & 15;
  const unsigned short* Qb = Q + (size_t)b * S_LEN * DMODEL + h * HEADD;
  const unsigned short* Kb = K + (size_t)b * S_LEN * DMODEL + h * HEADD;
  const unsigned short* Vtb = Vt + (size_t)bh * HEADD * S_LEN;

  // stage this head's bias row (4 KB bf16) into LDS; saturated-bucket const
  const float bconst =
      __uint_as_float((unsigned int)bias[h * S_LEN + 1024] << 16);
  {
    const bf16x8* src = (const bf16x8*)(bias + h * S_LEN);
    ((bf16x8*)bls)[tid] = src[tid];
  }

  auto stage = [&](int kv0, int bu) {
#pragma unroll
    for (int it = 0; it < 2; ++it) {
      int ti = it * 256 + tid;
      int row = ti >> 3, ch = ti & 7;
      int sch = ch ^ (row & 7);  // pre-swizzled source chunk
      gload_lds16(Kb + (size_t)(kv0 + row) * DMODEL + sch * 8,
                  (char*)Ks[bu] + (it * 256 + w * 64) * 16);
      gload_lds16(Vtb + (size_t)row * S_LEN + kv0 + sch * 8,
                  (char*)Vs[bu] + (it * 256 + w * 64) * 16);
    }
  };

  const int q0 = qt * 64;
  const int nt = qt + 1;
  const int wrow0 = q0 + w * 16;
  const int qglob = wrow0 + c;  // this lane's q row

  // Q fragments (B-operand rows) in registers
  bf16x8 aq[2];
#pragma unroll
  for (int kh = 0; kh < 2; ++kh)
    aq[kh] = *(const bf16x8*)(Qb + (size_t)qglob * DMODEL + kh * 32 + g * 8);

  f32x4 oacc[4] = {};
  float mreg = -1e30f, lreg = 0.f;

  __syncthreads();  // bls ready
  stage(0, 0);

#pragma unroll 1
  for (int t = 0; t < nt; ++t) {
    const int kv0 = t * 64;
    const int bu = t & 1;
    asm volatile("s_waitcnt vmcnt(0)" ::: "memory");
    __builtin_amdgcn_sched_barrier(0);
    __builtin_amdgcn_s_barrier();
    if (t + 1 < nt) stage((t + 1) * 64, bu ^ 1);

    // ---- S^T = K Q^T : D[row=k_local][col=q] ----
    f32x4 sac[4] = {};
    __builtin_amdgcn_s_setprio(1);
#pragma unroll
    for (int kh = 0; kh < 2; ++kh) {
      bf16x8 bk[4];
#pragma unroll
      for (int nf = 0; nf < 4; ++nf) {
        int row = nf * 16 + c;
        int off = (row * 128 + (kh * 4 + g) * 16) ^ ((row & 7) << 4);
        bk[nf] = *(const bf16x8*)((const char*)Ks[bu] + off);
      }
#pragma unroll
      for (int nf = 0; nf < 4; ++nf)
        sac[nf] = __builtin_amdgcn_mfma_f32_16x16x32_bf16(
            bk[nf], aq[kh], sac[nf], 0, 0, 0);
    }
    __builtin_amdgcn_s_setprio(0);

    // ---- bias + causal mask, exp2 domain (interior: const bias, no mask) ----
    float p[4][4];
    float pmax = -1e30f;
    const float qscale = 0.125f * LOG2E;
    if (kv0 + 176 <= wrow0) {  // wave-uniform: all dists >= 113 -> bucket 31
#pragma unroll
      for (int nf = 0; nf < 4; ++nf)
#pragma unroll
        for (int r = 0; r < 4; ++r) {
          float sv = sac[nf][r] * qscale + bconst;
          p[nf][r] = sv;
          pmax = fmaxf(pmax, sv);
        }
    } else {
#pragma unroll
      for (int nf = 0; nf < 4; ++nf)
#pragma unroll
        for (int r = 0; r < 4; ++r) {
          int kg = kv0 + nf * 16 + g * 4 + r;
          int d = qglob - kg;
          float bv = __uint_as_float((unsigned int)bls[d < 0 ? 0 : d] << 16);
          float sv = (d >= 0) ? sac[nf][r] * qscale + bv : -1e30f;
          p[nf][r] = sv;
          pmax = fmaxf(pmax, sv);
        }
    }
    pmax = fmaxf(pmax, __shfl_xor(pmax, 16));
    pmax = fmaxf(pmax, __shfl_xor(pmax, 32));

    // ---- online softmax, defer-max (skip rescale when growth <= 8/ln2) ----
    if (!__all(pmax - mreg <= 11.5f)) {
      float mnew = fmaxf(mreg, pmax);
      float scl = exp2f(mreg - mnew);
      lreg *= scl;
#pragma unroll
      for (int nh = 0; nh < 4; ++nh)
#pragma unroll
        for (int r = 0; r < 4; ++r) oacc[nh][r] *= scl;
      mreg = mnew;
    }
    float lsum = 0.f;
#pragma unroll
    for (int nf = 0; nf < 4; ++nf)
#pragma unroll
      for (int r = 0; r < 4; ++r) {
        float pv = exp2f(p[nf][r] - mreg);
        p[nf][r] = pv;
        lsum += pv;
      }
    lsum += __shfl_xor(lsum, 16);
    lsum += __shfl_xor(lsum, 32);
    lreg += lsum;

    // ---- P^T -> Ps[w] rows q (bf16, packed pairs, swizzled) ----
#pragma unroll
    for (int nf = 0; nf < 4; ++nf) {
      unsigned int u0 = pk_bf16(p[nf][0], p[nf][1]);
      unsigned int u1 = pk_bf16(p[nf][2], p[nf][3]);
      int off = (c * 128 + nf * 32 + g * 8) ^ ((c & 7) << 4);
      *(uint2*)((char*)Ps[w] + off) = make_uint2(u0, u1);
    }

    // ---- O^T += V^T P^T : mfma(A=Vt rows(hd), B=P rows(q)) ----
    __builtin_amdgcn_s_setprio(1);
#pragma unroll
    for (int kh = 0; kh < 2; ++kh) {
      bf16x8 pa, va[4];
      {
        int off = (c * 128 + kh * 64 + g * 16) ^ ((c & 7) << 4);
        pa = *(const bf16x8*)((const char*)Ps[w] + off);
      }
#pragma unroll
      for (int nh = 0; nh < 4; ++nh) {
        int row = nh * 16 + c;
        int off = (row * 128 + (kh * 4 + g) * 16) ^ ((row & 7) << 4);
        va[nh] = *(const bf16x8*)((const char*)Vs[bu] + off);
      }
#pragma unroll
      for (int nh = 0; nh < 4; ++nh)
        oacc[nh] = __builtin_amdgcn_mfma_f32_16x16x32_bf16(
            va[nh], pa, oacc[nh], 0, 0, 0);
    }
    __builtin_amdgcn_s_setprio(0);
  }

  // ---- epilogue: O^T -> Ps[w] (rows q, cols hd) -> coalesced global ----
  {
    float inv = 1.f / lreg;
#pragma unroll
    for (int nh = 0; nh < 4; ++nh) {
      unsigned int u0 = pk_bf16(oacc[nh][0] * inv, oacc[nh][1] * inv);
      unsigned int u1 = pk_bf16(oacc[nh][2] * inv, oacc[nh][3] * inv);
      int off = (c * 128 + nh * 32 + g * 8) ^ ((c & 7) << 4);
      *(uint2*)((char*)Ps[w] + off) = make_uint2(u0, u1);
    }
    int rowq = l >> 2, ch2 = l & 3;
    int off1 = (rowq * 128 + ch2 * 16) ^ ((rowq & 7) << 4);
    int off2 = (rowq * 128 + (ch2 + 4) * 16) ^ ((rowq & 7) << 4);
    bf16x8 o1 = *(const bf16x8*)((const char*)Ps[w] + off1);
    bf16x8 o2 = *(const bf16x8*)((const char*)Ps[w] + off2);
    unsigned short* orow =
        O + (size_t)(b * S_LEN + wrow0 + rowq) * DMODEL + h * HEADD;
    *(bf16x8*)(orow + ch2 * 8) = o1;
    *(bf16x8*)(orow + (ch2 + 4) * 8) = o2;
  }
}

// ---------- host launcher ----------
extern "C" void kernel_launch(void* const* d_in, const int* in_sizes, int n_in,
                              void* d_out, int out_size, void* d_ws, size_t ws_size,
                              hipStream_t stream) {
  const float* x   = (const float*)d_in[0];
  // d_in[1] causal_mask, d_in[2] padding_mask: causality implemented directly;
  // padding_mask is all-false in this problem.
  const float* Wq  = (const float*)d_in[3];
  const float* Wk  = (const float*)d_in[4];
  const float* Wv  = (const float*)d_in[5];
  const float* Wo  = (const float*)d_in[6];
  const float* rel = (const float*)d_in[7];
  float* out = (float*)d_out;

  char* ws = (char*)d_ws;
  const size_t MB = 1u << 20;
  unsigned short* xb  = (unsigned short*)(ws);            // 8 MB (x bf16)
  unsigned short* Oa  = xb;                               // alias: reused after QKV
  unsigned short* Qb  = (unsigned short*)(ws + 8 * MB);   // 8 MB
  unsigned short* Kb  = (unsigned short*)(ws + 16 * MB);  // 8 MB
  unsigned short* Vb  = (unsigned short*)(ws + 24 * MB);  // 8 MB
  unsigned short* Vtb = (unsigned short*)(ws + 32 * MB);  // 8 MB
  unsigned short* Wqb = (unsigned short*)(ws + 40 * MB);  // 2 MB
  unsigned short* Wkb = (unsigned short*)(ws + 42 * MB);  // 2 MB
  unsigned short* Wvb = (unsigned short*)(ws + 44 * MB);  // 2 MB
  unsigned short* Wob = (unsigned short*)(ws + 46 * MB);  // 2 MB
  unsigned short* bias = (unsigned short*)(ws + 48 * MB); // 64 KB (bf16)

  // fused prep: all fp32->bf16 conversions + bias table (1 launch)
  prep_kernel<<<8320, 256, 0, stream>>>(x, Wq, Wk, Wv, Wo, rel,
                                        xb, Wqb, Wkb, Wvb, Wob, bias);

  // Q, K, V projections (fused: grid.z selects weight/output)
  gemm_bt<unsigned short, 4><<<dim3(8, 32, 3), 256, 0, stream>>>(
      xb, Wqb, Wkb, Wvb, Qb, Kb, Vb, MROWS, DMODEL, DMODEL);

  // V -> Vt (B,H,HD,S) via LDS tiles
  vtrans_kernel<<<dim3(32, 32), 256, 0, stream>>>(Vb, Vtb);

  // attention (XCD-aware 1D grid, GLOBAL LPT per XCD, 3 blocks/CU)
  attn_kernel<<<1024, 256, 0, stream>>>(Qb, Kb, Vtb, bias, Oa);

  // output projection (fp32 out), BM=64 -> 512 blocks
  gemm_bt<float, 2><<<dim3(8, 64, 1), 256, 0, stream>>>(
      Oa, Wob, Wob, Wob, out, out, out, MROWS, DMODEL, DMODEL);
}